// Round 4
// baseline (83.093 us; speedup 1.0000x reference)
//
#include <hip/hip_runtime.h>

// GAT fused pipeline, round 3: counted-vmcnt software pipeline (T3+T4).
// Raw s_barrier + s_waitcnt vmcnt(N>0) so prefetches stay in flight across
// barriers (the R2 __syncthreads() vmcnt(0) drain was ~2.5x of step time).
//   h = x@W; s1 = x@(W@a1); s2 = x@(W@a2);  (score path exact fp32)
//   m_i = leaky(s1_i + max_j s2_j)          (leaky is monotone)
//   out_i = (sum_j exp(leaky(s1_i+s2_j)-m_i) h_j) / Z_i,  Z accumulated in k_pv.

typedef unsigned short u16;
typedef unsigned int   u32;
typedef float  f32x4  __attribute__((ext_vector_type(4)));
typedef __bf16 bf16x8 __attribute__((ext_vector_type(8)));
typedef __bf16 bf16x4 __attribute__((ext_vector_type(4)));

#define NB    64
#define NENT  1024
#define FD    256
#define NROWS (NB * NENT)
#define ALPHA 0.2f
#define LOG2E 1.4426950408889634f

// counted waits + raw barrier (compiler fence + sched fence for rule #18)
#define VMCNT(n)  asm volatile("s_waitcnt vmcnt(" #n ")" ::: "memory")
#define LGKMCNT0  asm volatile("s_waitcnt lgkmcnt(0)" ::: "memory")
#define BAR()                                                                  \
  do {                                                                         \
    __builtin_amdgcn_s_barrier();                                              \
    asm volatile("" ::: "memory");                                             \
    __builtin_amdgcn_sched_barrier(0);                                         \
  } while (0)

typedef __attribute__((address_space(1))) const void* gas_ptr;
typedef __attribute__((address_space(3))) void*       las_ptr;
__device__ __forceinline__ void gload16(const void* g, void* l) {
  __builtin_amdgcn_global_load_lds((gas_ptr)g, (las_ptr)l, 16, 0, 0);
}
__device__ __forceinline__ float fexp2(float x) {   // 2^x, 1-instr
  float r;
  asm("v_exp_f32 %0, %1" : "=v"(r) : "v"(x));
  return r;
}

// ---------------- k_wa: Wa1 = W@a1, Wa2 = W@a2 (fp32 exact) ----------------
__global__ __launch_bounds__(256) void k_wa(const float* __restrict__ W,
                                            const float* __restrict__ a,
                                            float* __restrict__ Wa1,
                                            float* __restrict__ Wa2) {
  const int k = blockIdx.x, f = threadIdx.x;
  const float w = W[(size_t)k * FD + f];
  float p1 = w * a[f];
  float p2 = w * a[FD + f];
#pragma unroll
  for (int off = 1; off < 64; off <<= 1) {
    p1 += __shfl_xor(p1, off, 64);
    p2 += __shfl_xor(p2, off, 64);
  }
  __shared__ float r1[4], r2[4];
  const int wv = f >> 6, lane = f & 63;
  if (lane == 0) { r1[wv] = p1; r2[wv] = p2; }
  __syncthreads();
  if (f == 0) {
    Wa1[k] = r1[0] + r1[1] + r1[2] + r1[3];
    Wa2[k] = r2[0] + r2[1] + r2[2] + r2[3];
  }
}

// ---------------- k_wt: Wt[f][k] = bf16(W[k][f]) ----------------
__global__ __launch_bounds__(256) void k_wt(const float* __restrict__ W,
                                            u16* __restrict__ Wt) {
  __shared__ float tile[64][65];
  const int t = threadIdx.x;
  const int ki = blockIdx.x >> 2, fi = blockIdx.x & 3;
  const int k0 = ki * 64, f0 = fi * 64;
  const int r = t >> 4, c4 = (t & 15) * 4;
#pragma unroll
  for (int it = 0; it < 4; ++it) {
    const int row = r + it * 16;
    float4 v = *(const float4*)&W[(size_t)(k0 + row) * FD + f0 + c4];
    tile[row][c4 + 0] = v.x; tile[row][c4 + 1] = v.y;
    tile[row][c4 + 2] = v.z; tile[row][c4 + 3] = v.w;
  }
  __syncthreads();
#pragma unroll
  for (int it = 0; it < 4; ++it) {
    const int fr = r + it * 16;
    bf16x4 pk;
    pk[0] = (__bf16)tile[c4 + 0][fr]; pk[1] = (__bf16)tile[c4 + 1][fr];
    pk[2] = (__bf16)tile[c4 + 2][fr]; pk[3] = (__bf16)tile[c4 + 3][fr];
    *(bf16x4*)&Wt[(size_t)(f0 + fr) * FD + k0 + c4] = pk;
  }
}

// ---------------- k_h: h_oct = bf16(x@W), s1, s2 (counted-vmcnt pipe) --------
__global__ __launch_bounds__(512, 2) void k_h(
    const float* __restrict__ x, const u16* __restrict__ Wt,
    const float* __restrict__ Wa1g, const float* __restrict__ Wa2g,
    u16* __restrict__ h_oct, float* __restrict__ s1, float* __restrict__ s2) {
  __shared__ __align__(16) u16 A_lds[2][4][256][8];   // [buf][kgrp][row][8]
  __shared__ __align__(16) u16 B_lds[2][4][256][8];   // [buf][kgrp][col][8]
  __shared__ float wa1[FD], wa2[FD];
  const int t = threadIdx.x;
  const int lane = t & 63, wv = t >> 6;
  const int wr = wv >> 2, wc = wv & 3;          // wave tile 128x64 (2x4 grid)
  const int g16 = lane >> 4, c15 = lane & 15;
  const int p = blockIdx.x;
  const int lb = (p & 7) * 32 + (p >> 3);       // XCD-chunked (same map as k_pv)
  const int rT = lb * 256;
  const int row = t >> 1, half = t & 1;         // staging: 2 thr/row, 16 k each
  const float* xsrc = x + (size_t)(rT + row) * FD + half * 16;
  float p1 = 0.f, p2 = 0.f;
  f32x4 acc[8][4];
  const f32x4 vz = {0.f, 0.f, 0.f, 0.f};
#pragma unroll
  for (int i = 0; i < 8; ++i)
#pragma unroll
    for (int j = 0; j < 4; ++j) acc[i][j] = vz;

  auto issueB = [&](int nb, int kc) {           // 2 x gload16 per thread
    const int k0n = kc * 32;
    const int d0 = t;
    gload16(Wt + (size_t)(d0 & 255) * FD + k0n + (d0 >> 8) * 8,
            (char*)(&B_lds[nb][0][0][0]) + d0 * 16);
    const int d1 = t + 512;
    gload16(Wt + (size_t)(d1 & 255) * FD + k0n + (d1 >> 8) * 8,
            (char*)(&B_lds[nb][0][0][0]) + d1 * 16);
  };
  auto stageA = [&](int nb, int kc, const float4* xr) {  // cvt + 2 ds_write
    bf16x8 w0, w1;
    w0[0] = (__bf16)xr[0].x; w0[1] = (__bf16)xr[0].y;
    w0[2] = (__bf16)xr[0].z; w0[3] = (__bf16)xr[0].w;
    w0[4] = (__bf16)xr[1].x; w0[5] = (__bf16)xr[1].y;
    w0[6] = (__bf16)xr[1].z; w0[7] = (__bf16)xr[1].w;
    w1[0] = (__bf16)xr[2].x; w1[1] = (__bf16)xr[2].y;
    w1[2] = (__bf16)xr[2].z; w1[3] = (__bf16)xr[2].w;
    w1[4] = (__bf16)xr[3].x; w1[5] = (__bf16)xr[3].y;
    w1[6] = (__bf16)xr[3].z; w1[7] = (__bf16)xr[3].w;
    *(bf16x8*)&A_lds[nb][half * 2][row][0] = w0;
    *(bf16x8*)&A_lds[nb][half * 2 + 1][row][0] = w1;
    const int kb = kc * 32 + half * 16;
#pragma unroll
    for (int q = 0; q < 4; ++q) {
      p1 += xr[q].x * wa1[kb + 4 * q + 0] + xr[q].y * wa1[kb + 4 * q + 1] +
            xr[q].z * wa1[kb + 4 * q + 2] + xr[q].w * wa1[kb + 4 * q + 3];
      p2 += xr[q].x * wa2[kb + 4 * q + 0] + xr[q].y * wa2[kb + 4 * q + 1] +
            xr[q].z * wa2[kb + 4 * q + 2] + xr[q].w * wa2[kb + 4 * q + 3];
    }
  };
  auto loadx = [&](float4* xr, int kc) {
    const float* s = xsrc + kc * 32;
    xr[0] = *(const float4*)(s);      xr[1] = *(const float4*)(s + 4);
    xr[2] = *(const float4*)(s + 8);  xr[3] = *(const float4*)(s + 12);
  };
  auto mfma_step = [&](int cb) {
    bf16x8 bfv[4];
#pragma unroll
    for (int fj = 0; fj < 4; ++fj)
      bfv[fj] = *(const bf16x8*)&B_lds[cb][g16][wc * 64 + fj * 16 + c15][0];
    __builtin_amdgcn_s_setprio(1);
#pragma unroll
    for (int fi = 0; fi < 8; ++fi) {
      bf16x8 af = *(const bf16x8*)&A_lds[cb][g16][wr * 128 + fi * 16 + c15][0];
#pragma unroll
      for (int fj = 0; fj < 4; ++fj)
        acc[fi][fj] = __builtin_amdgcn_mfma_f32_16x16x32_bf16(
            af, bfv[fj], acc[fi][fj], 0, 0, 0);
    }
    __builtin_amdgcn_s_setprio(0);
  };

  // ---- prologue ----
  if (t < FD) { wa1[t] = Wa1g[t]; wa2[t] = Wa2g[t]; }
  float4 xe[4], xo[4];
  loadx(xe, 0);                 // x chunk 0
  loadx(xo, 1);                 // x chunk 1
  issueB(0, 0);                 // Wt chunk 0
  LGKMCNT0;                     // wa ds_writes visible
  BAR();                        // barrier A (B0 + x loads still in flight)
  stageA(0, 0, xe);             // A[0]; consumes xe (compiler waits drain it)
  loadx(xe, 2);                 // x chunk 2
  LGKMCNT0;                     // A[0] ds_writes visible
  VMCNT(4);                     // drain through B0 (leaves new xe's 4 loads)
  BAR();                        // barrier B: step 0 ready

  // ---- 8 fully-unrolled K-steps; consume chunk k from buf k&1 ----
#pragma unroll
  for (int k = 0; k < 8; ++k) {
    if (k < 7) {
      issueB((k + 1) & 1, k + 1);
      float4* xr = (k & 1) ? xe : xo;        // chunk k+1 lives here
      stageA((k + 1) & 1, k + 1, xr);
      if (k + 3 < 8) loadx(xr, k + 3);       // refill freed slot
    }
    mfma_step(k & 1);
    if (k < 7) {
      LGKMCNT0;
      if (k + 3 < 8) VMCNT(4); else VMCNT(0);  // drain through B[k+1]
      BAR();
    }
  }
  // s1/s2: reduce 2 k-halves (xor 1)
  p1 += __shfl_xor(p1, 1, 64);
  p2 += __shfl_xor(p2, 1, 64);
  if (half == 0) { s1[rT + row] = p1; s2[rT + row] = p2; }
  // epilogue: h_oct[oct][col][row&7], 8B dense stores
#pragma unroll
  for (int fi = 0; fi < 8; ++fi) {
    const int rowb = rT + wr * 128 + fi * 16 + 4 * g16;
    const int oct = rowb >> 3, u = rowb & 7;    // u in {0,4}
#pragma unroll
    for (int fj = 0; fj < 4; ++fj) {
      const int col = wc * 64 + fj * 16 + c15;
      bf16x4 pk;
      pk[0] = (__bf16)acc[fi][fj][0]; pk[1] = (__bf16)acc[fi][fj][1];
      pk[2] = (__bf16)acc[fi][fj][2]; pk[3] = (__bf16)acc[fi][fj][3];
      *(bf16x4*)((u16*)h_oct + ((size_t)oct * FD + col) * 8 + u) = pk;
    }
  }
}

// ---------------- k_pv: out = softmax(e) @ h (counted-vmcnt pipe) ----------
__global__ __launch_bounds__(512, 2) void k_pv(
    const u16* __restrict__ h_oct, const float* __restrict__ s1,
    const float* __restrict__ s2, float* __restrict__ out) {
  __shared__ __align__(16) u16 P_lds[2][4][256][8];   // double buffer
  __shared__ __align__(16) u16 V_lds[3][4][256][8];   // triple buffer
  __shared__ float s2l[NENT];
  const int t = threadIdx.x;
  const int lane = t & 63, wv = t >> 6;
  const int wr = wv >> 2, wc = wv & 3;          // wave tile 128x64
  const int g16 = lane >> 4, c15 = lane & 15;
  const int p = blockIdx.x;
  const int lb = (p & 7) * 32 + (p >> 3);       // XCD-chunked: 8 batches/XCD
  const int b = lb >> 2, itile = lb & 3;
  const int i0 = itile * 256;
  const int irow = t & 255, gsl = t >> 8;       // p-gen: (i-row, j-half)
  const int rowg = b * NENT + i0 + irow;
  const size_t obase = (size_t)b * (NENT / 8);
  f32x4 acc[8][4];
  const f32x4 vz = {0.f, 0.f, 0.f, 0.f};
#pragma unroll
  for (int i = 0; i < 8; ++i)
#pragma unroll
    for (int j = 0; j < 4; ++j) acc[i][j] = vz;
  float zsum = 0.f;

  auto vload = [&](int nb, int ksn) {           // 2 x gload16 per thread
    const int j0n = ksn * 32;
    const int d0 = t;
    gload16(h_oct + ((obase + (j0n >> 3) + (d0 >> 8)) * FD + (d0 & 255)) * 8,
            (char*)(&V_lds[nb][0][0][0]) + d0 * 16);
    const int d1 = t + 512;
    gload16(h_oct + ((obase + (j0n >> 3) + (d1 >> 8)) * FD + (d1 & 255)) * 8,
            (char*)(&V_lds[nb][0][0][0]) + d1 * 16);
  };

  // ---- prologue: oldest-first issue so counted vmcnt drains correctly ----
  const float s1v = s1[rowg];                               // 1 load (oldest)
  float2 s2f = *(const float2*)&s2[(size_t)b * NENT + t * 2];  // 1 load
  vload(0, 0);                                              // 2 loads
  vload(1, 1);                                              // 2 loads
  *(float2*)&s2l[t * 2] = s2f;      // compiler vmcnt-waits s2f (drains s1v too)
  LGKMCNT0;
  BAR();                            // s2l visible; V0/V1 still in flight
  // m_i = leaky(s1_i + max_j s2_j)  (leaky monotone)
  float sm = s2l[lane];
#pragma unroll
  for (int j = 1; j < 16; ++j) sm = fmaxf(sm, s2l[lane + j * 64]);
#pragma unroll
  for (int off = 1; off < 64; off <<= 1) sm = fmaxf(sm, __shfl_xor(sm, off, 64));
  const float q = s1v + sm;
  const float mv = fmaxf(q, ALPHA * q);
  // exp2-domain: P = 2^(max(fma(s2j,C1,s1A), fma(s2j,C2,s1B)))
  const float C2v = ALPHA * LOG2E;
  const float mvC = mv * LOG2E;
  const float s1A = s1v * LOG2E - mvC;
  const float s1B = s1v * C2v - mvC;

  auto genp = [&](int nb, int ksn) {
    const int jb = ksn * 32 + gsl * 16;
    float4 qa = *(const float4*)&s2l[jb];
    float4 qb = *(const float4*)&s2l[jb + 4];
    float4 qc = *(const float4*)&s2l[jb + 8];
    float4 qd = *(const float4*)&s2l[jb + 12];
    float zp = 0.f;
    auto pg = [&](float s2j) -> float {
      float vA = fmaf(s2j, LOG2E, s1A);
      float vB = fmaf(s2j, C2v, s1B);
      float r = fexp2(fmaxf(vA, vB));
      zp += r;
      return r;
    };
    bf16x8 pw0, pw1;
    pw0[0] = (__bf16)pg(qa.x); pw0[1] = (__bf16)pg(qa.y);
    pw0[2] = (__bf16)pg(qa.z); pw0[3] = (__bf16)pg(qa.w);
    pw0[4] = (__bf16)pg(qb.x); pw0[5] = (__bf16)pg(qb.y);
    pw0[6] = (__bf16)pg(qb.z); pw0[7] = (__bf16)pg(qb.w);
    pw1[0] = (__bf16)pg(qc.x); pw1[1] = (__bf16)pg(qc.y);
    pw1[2] = (__bf16)pg(qc.z); pw1[3] = (__bf16)pg(qc.w);
    pw1[4] = (__bf16)pg(qd.x); pw1[5] = (__bf16)pg(qd.y);
    pw1[6] = (__bf16)pg(qd.z); pw1[7] = (__bf16)pg(qd.w);
    zsum += zp;
    *(bf16x8*)&P_lds[nb][2 * gsl][irow][0] = pw0;
    *(bf16x8*)&P_lds[nb][2 * gsl + 1][irow][0] = pw1;
  };
  auto mfma_step = [&](int pb, int vb) {
    bf16x8 bfv[4];
#pragma unroll
    for (int fj = 0; fj < 4; ++fj)
      bfv[fj] = *(const bf16x8*)&V_lds[vb][g16][wc * 64 + fj * 16 + c15][0];
    __builtin_amdgcn_s_setprio(1);
#pragma unroll
    for (int fi = 0; fi < 8; ++fi) {
      bf16x8 af = *(const bf16x8*)&P_lds[pb][g16][wr * 128 + fi * 16 + c15][0];
#pragma unroll
      for (int fj = 0; fj < 4; ++fj)
        acc[fi][fj] = __builtin_amdgcn_mfma_f32_16x16x32_bf16(
            af, bfv[fj], acc[fi][fj], 0, 0, 0);
    }
    __builtin_amdgcn_s_setprio(0);
  };

  genp(0, 0);
  LGKMCNT0;                         // P[0] ds_writes visible
  VMCNT(2);                         // V[0] landed; V[1]'s 2 loads in flight
  BAR();

  int rb = 0, wb = 2;               // V read/write buffer rotation (mod 3)
#pragma unroll 1
  for (int k = 0; k < 32; ++k) {
    if (k < 30) vload(wb, k + 2);   // depth-2 V prefetch
    if (k < 31) genp((k + 1) & 1, k + 1);
    mfma_step(k & 1, rb);
    if (k < 31) {
      LGKMCNT0;                     // P ds_writes visible
      if (k < 30) VMCNT(2);         // V[k+1] landed; V[k+2] stays in flight
      else        VMCNT(0);         // tail: drain V[31]
      BAR();
    }
    rb = (rb == 2) ? 0 : rb + 1;
    wb = (wb == 2) ? 0 : wb + 1;
  }
  __syncthreads();                  // full drain before aliasing P_lds
  // Z reduction (alias onto P_lds[0])
  float* zred = (float*)&P_lds[0][0][0][0];
  zred[gsl * 256 + irow] = zsum;
  __syncthreads();
  // epilogue: out = acc / Z
#pragma unroll
  for (int fi = 0; fi < 8; ++fi) {
    const int rloc = wr * 128 + fi * 16 + 4 * g16;
    float rz[4];
#pragma unroll
    for (int r = 0; r < 4; ++r)
      rz[r] = __builtin_amdgcn_rcpf(zred[rloc + r] + zred[256 + rloc + r]);
#pragma unroll
    for (int fj = 0; fj < 4; ++fj) {
      const int col = wc * 64 + fj * 16 + c15;
      float* o = out + ((size_t)b * NENT + i0 + rloc) * FD + col;
      o[0 * FD] = acc[fi][fj][0] * rz[0];
      o[1 * FD] = acc[fi][fj][1] * rz[1];
      o[2 * FD] = acc[fi][fj][2] * rz[2];
      o[3 * FD] = acc[fi][fj][3] * rz[3];
    }
  }
}

extern "C" void kernel_launch(void* const* d_in, const int* in_sizes, int n_in,
                              void* d_out, int out_size, void* d_ws, size_t ws_size,
                              hipStream_t stream) {
  const float* x = (const float*)d_in[0];
  const float* W = (const float*)d_in[1];
  const float* a = (const float*)d_in[2];
  float* out = (float*)d_out;

  char* ws = (char*)d_ws;
  u16*   h_oct = (u16*)ws;                       // 32 MB
  float* s1  = (float*)(ws + (size_t)33554432);  // 256 KB
  float* s2  = s1 + NROWS;                       // 256 KB
  float* Wa1 = s2 + NROWS;                       // 1 KB
  float* Wa2 = Wa1 + FD;                         // 1 KB
  u16*   Wt  = (u16*)(Wa2 + FD);                 // 128 KB

  k_wa<<<dim3(256), dim3(256), 0, stream>>>(W, a, Wa1, Wa2);
  k_wt<<<dim3(16), dim3(256), 0, stream>>>(W, Wt);
  k_h<<<dim3(256), dim3(512), 0, stream>>>(x, Wt, Wa1, Wa2, h_oct, s1, s2);
  k_pv<<<dim3(256), dim3(512), 0, stream>>>(h_oct, s1, s2, out);
}